// Round 3
// baseline (465.261 us; speedup 1.0000x reference)
//
#include <hip/hip_runtime.h>

#define NPTS 8192
#define DIM 128
#define NCLS 128
#define KSEL 17      // k+1 smallest define the threshold
#define CAPW 48      // per-(wave,row) sweep-2 candidate capacity (expected ~8 used)
#define BIG 3.0e38f

typedef short bf16x8 __attribute__((ext_vector_type(8)));
typedef float f32x4 __attribute__((ext_vector_type(4)));

__device__ __forceinline__ unsigned short f2bf(float f) {
  unsigned int u = __float_as_uint(f);
  u += 0x7fffu + ((u >> 16) & 1u);   // round-to-nearest-even
  return (unsigned short)(u >> 16);
}

// ---- fused prep: blocks 0..2047 build bf16 X + exact norms; block 2048 does class stats
__global__ void prep(const float* __restrict__ X, const long long* __restrict__ targets,
                     unsigned short* __restrict__ Xb, float* __restrict__ sqv,
                     int* __restrict__ tgt, int* __restrict__ ccount,
                     int* __restrict__ j0a, int* __restrict__ j1a) {
  const int tid = threadIdx.x;
  if (blockIdx.x == 2048) {
    __shared__ int cc[NCLS], c0[NCLS], c1[NCLS];
    if (tid < NCLS) { cc[tid] = 0; c0[tid] = 0x7fffffff; c1[tid] = 0x7fffffff; }
    __syncthreads();
    for (int j = tid; j < NPTS; j += 256) {
      int c = (int)targets[j];
      tgt[j] = c;
      atomicAdd(&cc[c], 1);
      atomicMin(&c0[c], j);
    }
    __syncthreads();
    for (int j = tid; j < NPTS; j += 256) {
      int c = (int)targets[j];
      if (j != c0[c]) atomicMin(&c1[c], j);
    }
    __syncthreads();
    if (tid < NCLS) { ccount[tid] = cc[tid]; j0a[tid] = c0[tid]; j1a[tid] = c1[tid]; }
    return;
  }
  const int w = tid >> 6, lane = tid & 63;
  const int gw = blockIdx.x * 4 + w;
  const float* xr = X + (size_t)gw * DIM;
  float a = xr[lane], b = xr[lane + 64];
  Xb[(size_t)gw * DIM + lane] = f2bf(a);
  Xb[(size_t)gw * DIM + lane + 64] = f2bf(b);
  float s = a * a + b * b;
#pragma unroll
  for (int off = 32; off; off >>= 1) s += __shfl_xor(s, off);
  if (lane == 0) sqv[gw] = s;
}

// ---- two-sweep kNN: grid 2048 = 512 row-groups x 4 column-quarters.
// Block = 4 waves; wave w scans cols [quarter*2048 + w*512, +512) in 32 16-col tiles.
// Sweep 1: per-lane min2 (registers) -> U = 17th of 128-subset (>= quarter t17).
// Sweep 2: re-stream GEMM, append d2 <= U (mask in sign bit), emit quarter's 17 smallest.
__global__ __launch_bounds__(256) void knn_main(
    const unsigned short* __restrict__ Xb, const float* __restrict__ sqv,
    const int* __restrict__ tgt, float* __restrict__ scr) {
  __shared__ float sh[3072];          // union: cand[16][128] (sweep1) / bufD[4][16][CAPW] (sweep2)
  __shared__ int   cnt[4][16];
  __shared__ float Uv[16];

  const int tid = threadIdx.x;
  const int w = tid >> 6;
  const int lane = tid & 63;
  const int quad = lane >> 4;
  const int l16 = lane & 15;
  const int rg = blockIdx.x >> 2;
  const int quarter = blockIdx.x & 3;
  const int rbase = rg * 16;
  const int colbase = quarter * 2048 + w * 512;

  // A fragments (16 rows x K=128), persistent. 16x16x32 bf16: A[m=lane&15][k=quad*8+j]
  bf16x8 afrag[4];
  {
    const unsigned short* arow = Xb + (size_t)(rbase + l16) * DIM + quad * 8;
#pragma unroll
    for (int kb = 0; kb < 4; kb++) afrag[kb] = *(const bf16x8*)(arow + kb * 32);
  }
  float sqi[4]; int ti[4];
#pragma unroll
  for (int r = 0; r < 4; r++) { int rr = rbase + quad * 4 + r; sqi[r] = sqv[rr]; ti[r] = tgt[rr]; }

  // wave-uniform tile index containing the diagonal (or -1)
  const int tdiag = (rbase >= colbase && rbase < colbase + 512) ? ((rbase - colbase) >> 4) : -1;

  // ---- sweep 1: per-lane two smallest d2 per row, software-pipelined
  float m1[4], m2[4];
#pragma unroll
  for (int r = 0; r < 4; r++) { m1[r] = BIG; m2[r] = BIG; }
  {
    const unsigned short* bp = Xb + (size_t)(colbase + l16) * DIM + quad * 8;
    bf16x8 bnx[4];
#pragma unroll
    for (int kb = 0; kb < 4; kb++) bnx[kb] = *(const bf16x8*)(bp + kb * 32);
    float sqn = sqv[colbase + l16];
    for (int t = 0; t < 32; t++) {
      bf16x8 bc[4];
#pragma unroll
      for (int kb = 0; kb < 4; kb++) bc[kb] = bnx[kb];
      const float sqj = sqn;
      if (t < 31) {                                    // prefetch next tile
        bp += 16 * DIM;
#pragma unroll
        for (int kb = 0; kb < 4; kb++) bnx[kb] = *(const bf16x8*)(bp + kb * 32);
        sqn = sqv[colbase + (t + 1) * 16 + l16];
      }
      f32x4 acc = {0.f, 0.f, 0.f, 0.f};
#pragma unroll
      for (int kb = 0; kb < 4; kb++)
        acc = __builtin_amdgcn_mfma_f32_16x16x32_bf16(afrag[kb], bc[kb], acc, 0, 0, 0);
      float d2v[4];
#pragma unroll
      for (int r = 0; r < 4; r++) d2v[r] = fmaf(-2.0f, acc[r], sqi[r] + sqj);
      if (t == tdiag) {                                // rare, wave-uniform
#pragma unroll
        for (int r = 0; r < 4; r++) if (l16 == quad * 4 + r) d2v[r] = BIG;
      }
#pragma unroll
      for (int r = 0; r < 4; r++) {
        m2[r] = fminf(m2[r], fmaxf(m1[r], d2v[r]));
        m1[r] = fminf(m1[r], d2v[r]);
      }
    }
  }
  // publish min2 candidates: per row 4 waves x 16 lanes x 2 = 128 elements
#pragma unroll
  for (int r = 0; r < 4; r++) {
    int row = quad * 4 + r;
    sh[row * 128 + w * 32 + l16 * 2] = m1[r];
    sh[row * 128 + w * 32 + l16 * 2 + 1] = m2[r];
  }
  __syncthreads();

  // U[row] = 17th smallest of the 128-candidate subset
  for (int ri = 0; ri < 4; ri++) {
    int row = w * 4 + ri;
    float a = sh[row * 128 + lane], b = sh[row * 128 + 64 + lane];
    float v17 = BIG;
    for (int round = 0; round < KSEL; round++) {
      float v = a; int idx = lane;
      if (b < v) { v = b; idx = lane | 64; }
#pragma unroll
      for (int off = 32; off; off >>= 1) {
        float ov = __shfl_xor(v, off);
        int   oi = __shfl_xor(idx, off);
        if (ov < v || (ov == v && oi < idx)) { v = ov; idx = oi; }
      }
      if ((idx & 63) == lane) { if (idx & 64) b = BIG; else a = BIG; }
      v17 = v;
    }
    if (lane == 0) Uv[row] = v17;
  }
  __syncthreads();
  float Ur[4];
#pragma unroll
  for (int r = 0; r < 4; r++) Ur[r] = Uv[quad * 4 + r];
  if (lane < 16) cnt[w][lane] = 0;   // wave-local, in-order with this wave's later atomics

  // ---- sweep 2: append d2 <= U (sign bit = same-class flag)
  {
    const unsigned short* bp = Xb + (size_t)(colbase + l16) * DIM + quad * 8;
    bf16x8 bnx[4];
#pragma unroll
    for (int kb = 0; kb < 4; kb++) bnx[kb] = *(const bf16x8*)(bp + kb * 32);
    float sqn = sqv[colbase + l16];
    int tjn = tgt[colbase + l16];
    for (int t = 0; t < 32; t++) {
      bf16x8 bc[4];
#pragma unroll
      for (int kb = 0; kb < 4; kb++) bc[kb] = bnx[kb];
      const float sqj = sqn;
      const int tj = tjn;
      if (t < 31) {
        bp += 16 * DIM;
#pragma unroll
        for (int kb = 0; kb < 4; kb++) bnx[kb] = *(const bf16x8*)(bp + kb * 32);
        sqn = sqv[colbase + (t + 1) * 16 + l16];
        tjn = tgt[colbase + (t + 1) * 16 + l16];
      }
      f32x4 acc = {0.f, 0.f, 0.f, 0.f};
#pragma unroll
      for (int kb = 0; kb < 4; kb++)
        acc = __builtin_amdgcn_mfma_f32_16x16x32_bf16(afrag[kb], bc[kb], acc, 0, 0, 0);
      float d2v[4];
#pragma unroll
      for (int r = 0; r < 4; r++) d2v[r] = fmaf(-2.0f, acc[r], sqi[r] + sqj);
      if (t == tdiag) {
#pragma unroll
        for (int r = 0; r < 4; r++) if (l16 == quad * 4 + r) d2v[r] = BIG;
      }
#pragma unroll
      for (int r = 0; r < 4; r++) {
        if (d2v[r] <= Ur[r]) {
          int rl = quad * 4 + r;
          int pos = atomicAdd(&cnt[w][rl], 1);
          if (pos < CAPW) {
            unsigned enc = __float_as_uint(fmaxf(d2v[r], 0.0f));
            if (tj == ti[r]) enc |= 0x80000000u;
            sh[(w * 16 + rl) * CAPW + pos] = __uint_as_float(enc);
          }
        }
      }
    }
  }
  __syncthreads();

  // ---- finalize: per row, the quarter's 17 smallest (encoded) -> global scratch
  for (int ri = 0; ri < 4; ri++) {
    const int rl = w * 4 + ri;
    const int grow = rbase + rl;
    float e[4]; int m[4];
#pragma unroll
    for (int ww = 0; ww < 4; ww++) {
      int n = min(cnt[ww][rl], CAPW);
      if (lane < n) {
        unsigned u = __float_as_uint(sh[(ww * 16 + rl) * CAPW + lane]);
        m[ww] = (int)(u >> 31); e[ww] = __uint_as_float(u & 0x7fffffffu);
      } else { e[ww] = BIG; m[ww] = 0; }
    }
    float* srow = scr + (size_t)grow * (4 * KSEL) + quarter * KSEL;
    for (int round = 0; round < KSEL; round++) {
      float v = e[0]; int idx = lane;
      if (e[1] < v) { v = e[1]; idx = lane | (1 << 6); }
      if (e[2] < v) { v = e[2]; idx = lane | (2 << 6); }
      if (e[3] < v) { v = e[3]; idx = lane | (3 << 6); }
#pragma unroll
      for (int off = 32; off; off >>= 1) {
        float ov = __shfl_xor(v, off);
        int   oi = __shfl_xor(idx, off);
        if (ov < v || (ov == v && oi < idx)) { v = ov; idx = oi; }
      }
      if ((idx & 63) == lane) {
        int s = idx >> 6;
        unsigned ub = __float_as_uint(e[s]);
        if (m[s]) ub |= 0x80000000u;
        srow[round] = __uint_as_float(ub);
        e[s] = BIG;
      }
    }
  }
}

// ---- per-row merge of 4 quarter-lists (68 candidates) + loss epilogue
__global__ __launch_bounds__(256) void knn_merge(
    const float* __restrict__ scr, const float* __restrict__ sqv,
    const int* __restrict__ tgt, const int* __restrict__ ccount,
    const int* __restrict__ j0a, const int* __restrict__ j1a,
    const float* __restrict__ X32, float* __restrict__ out) {
  __shared__ float blockAcc[4];
  const int tid = threadIdx.x;
  const int w = tid >> 6;
  const int lane = tid & 63;
  if (tid < 4) blockAcc[tid] = 0.0f;
  __syncthreads();
  for (int ri = 0; ri < 4; ri++) {
    const int grow = blockIdx.x * 16 + w * 4 + ri;
    const float* srow = scr + (size_t)grow * (4 * KSEL);
    unsigned u0 = __float_as_uint(srow[lane]);            // entries 0..63
    int mm0 = (int)(u0 >> 31); float e0 = __uint_as_float(u0 & 0x7fffffffu);
    float e1 = BIG; int mm1 = 0;
    if (lane < 4) {                                       // entries 64..67
      unsigned u1 = __float_as_uint(srow[64 + lane]);
      mm1 = (int)(u1 >> 31); e1 = __uint_as_float(u1 & 0x7fffffffu);
    }
    // exact 17th smallest of the union
    float a = e0, b = e1, t17 = BIG;
    for (int round = 0; round < KSEL; round++) {
      float v = a; int idx = lane;
      if (b < v) { v = b; idx = lane | 64; }
#pragma unroll
      for (int off = 32; off; off >>= 1) {
        float ov = __shfl_xor(v, off);
        int   oi = __shfl_xor(idx, off);
        if (ov < v || (ov == v && oi < idx)) { v = ov; idx = oi; }
      }
      if ((idx & 63) == lane) { if (idx & 64) b = BIG; else a = BIG; }
      t17 = v;
    }
    bool s0 = (e0 < t17), s1 = (e1 < t17);                // strict, matches reference
    float x0 = s0 ? expf(-sqrtf(fmaxf(e0, 1e-12f))) : 0.0f;
    float x1 = s1 ? expf(-sqrtf(fmaxf(e1, 1e-12f))) : 0.0f;
    float pls = (s0 && mm0 ? x0 : 0.0f) + (s1 && mm1 ? x1 : 0.0f);
    float nls = (s0 && !mm0 ? x0 : 0.0f) + (s1 && !mm1 ? x1 : 0.0f);
    int cp = (s0 && mm0) + (s1 && mm1);
    int cn = (s0 && !mm0) + (s1 && !mm1);
#pragma unroll
    for (int off = 32; off; off >>= 1) {
      pls += __shfl_xor(pls, off); nls += __shfl_xor(nls, off);
      cp  += __shfl_xor(cp, off);  cn  += __shfl_xor(cn, off);
    }
    const int c = tgt[grow];
    const int ncl = ccount[c];
    const bool valid = (ncl > 1) && (ncl < NPTS);
    if (valid) {
      float pos_eff;
      if (cp == 0) {
        const int jf = (grow == j0a[c]) ? j1a[c] : j0a[c];
        const float* xi = X32 + (size_t)grow * DIM;
        const float* xj = X32 + (size_t)jf * DIM;
        float pp = xi[lane] * xj[lane] + xi[lane + 64] * xj[lane + 64];
#pragma unroll
        for (int off = 32; off; off >>= 1) pp += __shfl_xor(pp, off);
        const float fb2 = sqv[grow] + sqv[jf] - 2.0f * pp;
        pos_eff = expf(-sqrtf(fmaxf(fb2, 1e-12f)));
      } else {
        pos_eff = pls;
      }
      if (lane == 0) {
        const float loss_i = -logf(pos_eff / (pos_eff + nls));
        const int cpa = (cp == 0) ? 1 : cp;
        atomicAdd(&blockAcc[0], loss_i);
        atomicAdd(&blockAcc[1], (cpa > cn) ? 1.0f : 0.0f);
        atomicAdd(&blockAcc[2], (float)cp);
        atomicAdd(&blockAcc[3], (float)cn);
      }
    }
  }
  __syncthreads();
  if (tid < 4) atomicAdd(&out[tid], blockAcc[tid] * (1.0f / (float)NPTS));
}

extern "C" void kernel_launch(void* const* d_in, const int* in_sizes, int n_in,
                              void* d_out, int out_size, void* d_ws, size_t ws_size,
                              hipStream_t stream) {
  const float* X = (const float*)d_in[0];
  const long long* targets = (const long long*)d_in[1];
  float* out = (float*)d_out;

  char* ws = (char*)d_ws;
  unsigned short* Xb = (unsigned short*)ws;                        // 2 MiB
  float* sqv  = (float*)(ws + (2u << 20));                         // 32 KiB
  int*   tgt  = (int*)  (ws + (2u << 20) + (32u << 10));           // 32 KiB
  int* ccount = (int*)  (ws + (2u << 20) + (64u << 10));           // 1.5 KiB
  int* j0a = ccount + NCLS;
  int* j1a = j0a + NCLS;
  float* scr = (float*)(ws + (2u << 20) + (128u << 10));           // 8192*68*4 = 2.2 MiB

  hipMemsetAsync(d_out, 0, 4 * sizeof(float), stream);
  prep<<<2049, 256, 0, stream>>>(X, targets, Xb, sqv, tgt, ccount, j0a, j1a);
  knn_main<<<2048, 256, 0, stream>>>(Xb, sqv, tgt, scr);
  knn_merge<<<512, 256, 0, stream>>>(scr, sqv, tgt, ccount, j0a, j1a, X, out);
}

// Round 4
// 388.142 us; speedup vs baseline: 1.1987x; 1.1987x over previous
//
#include <hip/hip_runtime.h>

#define NPTS 8192
#define DIM 128
#define NCLS 128
#define KSEL 17      // k+1 smallest define the threshold
#define CAPW 48      // per-(wave,row) LDS candidate capacity
#define SEG  40      // per-(row,half) scratch segment (raw-write limit)
#define NT   64      // tiles per wave (1024 cols / 16)
#define BIG 3.0e38f

typedef short bf16x8 __attribute__((ext_vector_type(8)));
typedef float f32x4 __attribute__((ext_vector_type(4)));

__device__ __forceinline__ unsigned short f2bf(float f) {
  unsigned int u = __float_as_uint(f);
  u += 0x7fffu + ((u >> 16) & 1u);   // round-to-nearest-even
  return (unsigned short)(u >> 16);
}

// ---- fused prep: blocks 0..2047 build bf16 X + exact norms; block 2048 does class stats
__global__ void prep(const float* __restrict__ X, const long long* __restrict__ targets,
                     unsigned short* __restrict__ Xb, float* __restrict__ sqv,
                     int* __restrict__ tgt, int* __restrict__ ccount,
                     int* __restrict__ j0a, int* __restrict__ j1a) {
  const int tid = threadIdx.x;
  if (blockIdx.x == 2048) {
    __shared__ int cc[NCLS], c0[NCLS], c1[NCLS];
    if (tid < NCLS) { cc[tid] = 0; c0[tid] = 0x7fffffff; c1[tid] = 0x7fffffff; }
    __syncthreads();
    for (int j = tid; j < NPTS; j += 256) {
      int c = (int)targets[j];
      tgt[j] = c;
      atomicAdd(&cc[c], 1);
      atomicMin(&c0[c], j);
    }
    __syncthreads();
    for (int j = tid; j < NPTS; j += 256) {
      int c = (int)targets[j];
      if (j != c0[c]) atomicMin(&c1[c], j);
    }
    __syncthreads();
    if (tid < NCLS) { ccount[tid] = cc[tid]; j0a[tid] = c0[tid]; j1a[tid] = c1[tid]; }
    return;
  }
  const int w = tid >> 6, lane = tid & 63;
  const int gw = blockIdx.x * 4 + w;
  const float* xr = X + (size_t)gw * DIM;
  float a = xr[lane], b = xr[lane + 64];
  Xb[(size_t)gw * DIM + lane] = f2bf(a);
  Xb[(size_t)gw * DIM + lane + 64] = f2bf(b);
  float s = a * a + b * b;
#pragma unroll
  for (int off = 32; off; off >>= 1) s += __shfl_xor(s, off);
  if (lane == 0) sqv[gw] = s;
}

// ---- two-sweep kNN: grid 1024 = 512 row-groups x 2 column-halves.
// Block = 4 waves; wave w scans cols [half*4096 + w*1024, +1024) in 64 16-col tiles.
// Sweep 1: per-lane min2 (registers) -> U = 17th of 128-subset (>= half t17).
// Sweep 2: re-stream GEMM, append d2 <= U (mask in sign bit).
// Finalize: raw-copy candidate lists (+count) to scratch; merge kernel selects.
__global__ __launch_bounds__(256, 4) void knn_main(
    const unsigned short* __restrict__ Xb, const float* __restrict__ sqv,
    const int* __restrict__ tgt, float* __restrict__ scr, int* __restrict__ cscr) {
  __shared__ float sh[3072];          // union: cand[16][128] (sweep1) / bufD[4][16][CAPW] (sweep2)
  __shared__ int   cnt[4][16];
  __shared__ float Uv[16];

  const int tid = threadIdx.x;
  const int w = tid >> 6;
  const int lane = tid & 63;
  const int quad = lane >> 4;
  const int l16 = lane & 15;
  const int rg = blockIdx.x >> 1;
  const int half = blockIdx.x & 1;
  const int rbase = rg * 16;
  const int colbase = half * 4096 + w * 1024;

  // A fragments (16 rows x K=128), persistent. 16x16x32 bf16: A[m=lane&15][k=quad*8+j]
  bf16x8 afrag[4];
  {
    const unsigned short* arow = Xb + (size_t)(rbase + l16) * DIM + quad * 8;
#pragma unroll
    for (int kb = 0; kb < 4; kb++) afrag[kb] = *(const bf16x8*)(arow + kb * 32);
  }
  float sqi[4]; int ti[4];
#pragma unroll
  for (int r = 0; r < 4; r++) { int rr = rbase + quad * 4 + r; sqi[r] = sqv[rr]; ti[r] = tgt[rr]; }

  // wave-uniform tile index containing the diagonal (or -1)
  const int tdiag = (rbase >= colbase && rbase < colbase + 1024) ? ((rbase - colbase) >> 4) : -1;

  const unsigned short* bbase = Xb + (size_t)(colbase + l16) * DIM + quad * 8;
  const float* sqp = sqv + colbase + l16;
  const int*   tgp = tgt + colbase + l16;

  // ---- sweep 1: per-lane two smallest d2 per row; register double-buffered
  float m1[4], m2[4];
#pragma unroll
  for (int r = 0; r < 4; r++) { m1[r] = BIG; m2[r] = BIG; }
  {
    bf16x8 bA[4], bB[4]; float sqA, sqB;
#pragma unroll
    for (int kb = 0; kb < 4; kb++) bA[kb] = *(const bf16x8*)(bbase + kb * 32);
    sqA = sqp[0];
    for (int t = 0; t < NT; t += 2) {
      {
        const int tn = (t + 1 < NT) ? t + 1 : NT - 1;
        const unsigned short* p = bbase + (size_t)tn * (16 * DIM);
#pragma unroll
        for (int kb = 0; kb < 4; kb++) bB[kb] = *(const bf16x8*)(p + kb * 32);
        sqB = sqp[tn * 16];
      }
      {
        f32x4 acc = {0.f, 0.f, 0.f, 0.f};
#pragma unroll
        for (int kb = 0; kb < 4; kb++)
          acc = __builtin_amdgcn_mfma_f32_16x16x32_bf16(afrag[kb], bA[kb], acc, 0, 0, 0);
        float d2v[4];
#pragma unroll
        for (int r = 0; r < 4; r++) d2v[r] = fmaf(-2.0f, acc[r], sqi[r] + sqA);
        if (t == tdiag) {
#pragma unroll
          for (int r = 0; r < 4; r++) if (l16 == quad * 4 + r) d2v[r] = BIG;
        }
#pragma unroll
        for (int r = 0; r < 4; r++) {
          m2[r] = fminf(m2[r], fmaxf(m1[r], d2v[r]));
          m1[r] = fminf(m1[r], d2v[r]);
        }
      }
      {
        const int tn = (t + 2 < NT) ? t + 2 : NT - 1;
        const unsigned short* p = bbase + (size_t)tn * (16 * DIM);
#pragma unroll
        for (int kb = 0; kb < 4; kb++) bA[kb] = *(const bf16x8*)(p + kb * 32);
        sqA = sqp[tn * 16];
      }
      {
        f32x4 acc = {0.f, 0.f, 0.f, 0.f};
#pragma unroll
        for (int kb = 0; kb < 4; kb++)
          acc = __builtin_amdgcn_mfma_f32_16x16x32_bf16(afrag[kb], bB[kb], acc, 0, 0, 0);
        float d2v[4];
#pragma unroll
        for (int r = 0; r < 4; r++) d2v[r] = fmaf(-2.0f, acc[r], sqi[r] + sqB);
        if (t + 1 == tdiag) {
#pragma unroll
          for (int r = 0; r < 4; r++) if (l16 == quad * 4 + r) d2v[r] = BIG;
        }
#pragma unroll
        for (int r = 0; r < 4; r++) {
          m2[r] = fminf(m2[r], fmaxf(m1[r], d2v[r]));
          m1[r] = fminf(m1[r], d2v[r]);
        }
      }
    }
  }
  // publish min2 candidates: per row 4 waves x 16 lanes x 2 = 128 elements
#pragma unroll
  for (int r = 0; r < 4; r++) {
    int row = quad * 4 + r;
    sh[row * 128 + w * 32 + l16 * 2] = m1[r];
    sh[row * 128 + w * 32 + l16 * 2 + 1] = m2[r];
  }
  __syncthreads();

  // U[row] = 17th smallest of the 128-candidate subset (>= true half t17)
  for (int ri = 0; ri < 4; ri++) {
    int row = w * 4 + ri;
    float a = sh[row * 128 + lane], b = sh[row * 128 + 64 + lane];
    float v17 = BIG;
    for (int round = 0; round < KSEL; round++) {
      float v = a; int idx = lane;
      if (b < v) { v = b; idx = lane | 64; }
#pragma unroll
      for (int off = 32; off; off >>= 1) {
        float ov = __shfl_xor(v, off);
        int   oi = __shfl_xor(idx, off);
        if (ov < v || (ov == v && oi < idx)) { v = ov; idx = oi; }
      }
      if ((idx & 63) == lane) { if (idx & 64) b = BIG; else a = BIG; }
      v17 = v;
    }
    if (lane == 0) Uv[row] = v17;
  }
  __syncthreads();
  float Ur[4];
#pragma unroll
  for (int r = 0; r < 4; r++) Ur[r] = Uv[quad * 4 + r];
  if (lane < 16) cnt[w][lane] = 0;

  // ---- sweep 2: append d2 <= U (sign bit = same-class flag); double-buffered
  {
    bf16x8 bA[4], bB[4]; float sqA, sqB; int tjA, tjB;
#pragma unroll
    for (int kb = 0; kb < 4; kb++) bA[kb] = *(const bf16x8*)(bbase + kb * 32);
    sqA = sqp[0]; tjA = tgp[0];
    for (int t = 0; t < NT; t += 2) {
      {
        const int tn = (t + 1 < NT) ? t + 1 : NT - 1;
        const unsigned short* p = bbase + (size_t)tn * (16 * DIM);
#pragma unroll
        for (int kb = 0; kb < 4; kb++) bB[kb] = *(const bf16x8*)(p + kb * 32);
        sqB = sqp[tn * 16]; tjB = tgp[tn * 16];
      }
      {
        f32x4 acc = {0.f, 0.f, 0.f, 0.f};
#pragma unroll
        for (int kb = 0; kb < 4; kb++)
          acc = __builtin_amdgcn_mfma_f32_16x16x32_bf16(afrag[kb], bA[kb], acc, 0, 0, 0);
        float d2v[4];
#pragma unroll
        for (int r = 0; r < 4; r++) d2v[r] = fmaf(-2.0f, acc[r], sqi[r] + sqA);
        if (t == tdiag) {
#pragma unroll
          for (int r = 0; r < 4; r++) if (l16 == quad * 4 + r) d2v[r] = BIG;
        }
        bool any = (d2v[0] <= Ur[0]) | (d2v[1] <= Ur[1]) | (d2v[2] <= Ur[2]) | (d2v[3] <= Ur[3]);
        if (__any(any)) {
#pragma unroll
          for (int r = 0; r < 4; r++) {
            if (d2v[r] <= Ur[r]) {
              int rl = quad * 4 + r;
              int pos = atomicAdd(&cnt[w][rl], 1);
              if (pos < CAPW) {
                unsigned enc = __float_as_uint(fmaxf(d2v[r], 0.0f));
                if (tjA == ti[r]) enc |= 0x80000000u;
                sh[(w * 16 + rl) * CAPW + pos] = __uint_as_float(enc);
              }
            }
          }
        }
      }
      {
        const int tn = (t + 2 < NT) ? t + 2 : NT - 1;
        const unsigned short* p = bbase + (size_t)tn * (16 * DIM);
#pragma unroll
        for (int kb = 0; kb < 4; kb++) bA[kb] = *(const bf16x8*)(p + kb * 32);
        sqA = sqp[tn * 16]; tjA = tgp[tn * 16];
      }
      {
        f32x4 acc = {0.f, 0.f, 0.f, 0.f};
#pragma unroll
        for (int kb = 0; kb < 4; kb++)
          acc = __builtin_amdgcn_mfma_f32_16x16x32_bf16(afrag[kb], bB[kb], acc, 0, 0, 0);
        float d2v[4];
#pragma unroll
        for (int r = 0; r < 4; r++) d2v[r] = fmaf(-2.0f, acc[r], sqi[r] + sqB);
        if (t + 1 == tdiag) {
#pragma unroll
          for (int r = 0; r < 4; r++) if (l16 == quad * 4 + r) d2v[r] = BIG;
        }
        bool any = (d2v[0] <= Ur[0]) | (d2v[1] <= Ur[1]) | (d2v[2] <= Ur[2]) | (d2v[3] <= Ur[3]);
        if (__any(any)) {
#pragma unroll
          for (int r = 0; r < 4; r++) {
            if (d2v[r] <= Ur[r]) {
              int rl = quad * 4 + r;
              int pos = atomicAdd(&cnt[w][rl], 1);
              if (pos < CAPW) {
                unsigned enc = __float_as_uint(fmaxf(d2v[r], 0.0f));
                if (tjB == ti[r]) enc |= 0x80000000u;
                sh[(w * 16 + rl) * CAPW + pos] = __uint_as_float(enc);
              }
            }
          }
        }
      }
    }
  }
  __syncthreads();

  // ---- finalize: raw-copy candidate lists (common) or 17-extract (overflow, rare)
  for (int rl = 0; rl < 16; rl++) {
    const int c0 = min(cnt[0][rl], CAPW), c1 = min(cnt[1][rl], CAPW),
              c2 = min(cnt[2][rl], CAPW), c3 = min(cnt[3][rl], CAPW);
    const int tot = c0 + c1 + c2 + c3;
    const int grow = rbase + rl;
    float* srow = scr + (size_t)grow * (2 * SEG) + half * SEG;
    if (tot <= SEG) {
      const int pre = (w > 0 ? c0 : 0) + (w > 1 ? c1 : 0) + (w > 2 ? c2 : 0);
      const int myc = (w == 0) ? c0 : ((w == 1) ? c1 : ((w == 2) ? c2 : c3));
      if (lane < myc) srow[pre + lane] = sh[(w * 16 + rl) * CAPW + lane];
      if (tid == 0) cscr[grow * 2 + half] = tot;
    } else if (w == (rl & 3)) {
      float e[4]; int m[4];
#pragma unroll
      for (int ww = 0; ww < 4; ww++) {
        int n = min(cnt[ww][rl], CAPW);
        if (lane < n) {
          unsigned u = __float_as_uint(sh[(ww * 16 + rl) * CAPW + lane]);
          m[ww] = (int)(u >> 31); e[ww] = __uint_as_float(u & 0x7fffffffu);
        } else { e[ww] = BIG; m[ww] = 0; }
      }
      for (int round = 0; round < KSEL; round++) {
        float v = e[0]; int idx = lane;
        if (e[1] < v) { v = e[1]; idx = lane | (1 << 6); }
        if (e[2] < v) { v = e[2]; idx = lane | (2 << 6); }
        if (e[3] < v) { v = e[3]; idx = lane | (3 << 6); }
#pragma unroll
        for (int off = 32; off; off >>= 1) {
          float ov = __shfl_xor(v, off);
          int   oi = __shfl_xor(idx, off);
          if (ov < v || (ov == v && oi < idx)) { v = ov; idx = oi; }
        }
        if ((idx & 63) == lane) {
          int s = idx >> 6;
          unsigned ub = __float_as_uint(e[s]);
          if (m[s]) ub |= 0x80000000u;
          srow[round] = __uint_as_float(ub);
          e[s] = BIG;
        }
      }
      if (lane == 0) cscr[grow * 2 + half] = KSEL;
    }
  }
}

// ---- per-row merge of the two half-lists (<=80 candidates) + loss epilogue
__global__ __launch_bounds__(256) void knn_merge(
    const float* __restrict__ scr, const int* __restrict__ cscr,
    const float* __restrict__ sqv, const int* __restrict__ tgt,
    const int* __restrict__ ccount, const int* __restrict__ j0a,
    const int* __restrict__ j1a, const float* __restrict__ X32,
    float* __restrict__ out) {
  __shared__ float blockAcc[4];
  const int tid = threadIdx.x;
  const int w = tid >> 6;
  const int lane = tid & 63;
  if (tid < 4) blockAcc[tid] = 0.0f;
  __syncthreads();
  for (int ri = 0; ri < 4; ri++) {
    const int grow = blockIdx.x * 16 + w * 4 + ri;
    const float* srow = scr + (size_t)grow * (2 * SEG);
    const int c0 = cscr[grow * 2], c1 = cscr[grow * 2 + 1];
    float e0 = BIG, e1 = BIG; int mm0 = 0, mm1 = 0;
    if (lane < c0) {
      unsigned u = __float_as_uint(srow[lane]);
      mm0 = (int)(u >> 31); e0 = __uint_as_float(u & 0x7fffffffu);
    }
    if (lane < c1) {
      unsigned u = __float_as_uint(srow[SEG + lane]);
      mm1 = (int)(u >> 31); e1 = __uint_as_float(u & 0x7fffffffu);
    }
    // exact 17th smallest of the union
    float a = e0, b = e1, t17 = BIG;
    for (int round = 0; round < KSEL; round++) {
      float v = a; int idx = lane;
      if (b < v) { v = b; idx = lane | 64; }
#pragma unroll
      for (int off = 32; off; off >>= 1) {
        float ov = __shfl_xor(v, off);
        int   oi = __shfl_xor(idx, off);
        if (ov < v || (ov == v && oi < idx)) { v = ov; idx = oi; }
      }
      if ((idx & 63) == lane) { if (idx & 64) b = BIG; else a = BIG; }
      t17 = v;
    }
    bool s0 = (e0 < t17), s1 = (e1 < t17);                // strict, matches reference
    float x0 = s0 ? expf(-sqrtf(fmaxf(e0, 1e-12f))) : 0.0f;
    float x1 = s1 ? expf(-sqrtf(fmaxf(e1, 1e-12f))) : 0.0f;
    float pls = (s0 && mm0 ? x0 : 0.0f) + (s1 && mm1 ? x1 : 0.0f);
    float nls = (s0 && !mm0 ? x0 : 0.0f) + (s1 && !mm1 ? x1 : 0.0f);
    int cp = (s0 && mm0) + (s1 && mm1);
    int cn = (s0 && !mm0) + (s1 && !mm1);
#pragma unroll
    for (int off = 32; off; off >>= 1) {
      pls += __shfl_xor(pls, off); nls += __shfl_xor(nls, off);
      cp  += __shfl_xor(cp, off);  cn  += __shfl_xor(cn, off);
    }
    const int c = tgt[grow];
    const int ncl = ccount[c];
    const bool valid = (ncl > 1) && (ncl < NPTS);
    if (valid) {
      float pos_eff;
      if (cp == 0) {
        const int jf = (grow == j0a[c]) ? j1a[c] : j0a[c];
        const float* xi = X32 + (size_t)grow * DIM;
        const float* xj = X32 + (size_t)jf * DIM;
        float pp = xi[lane] * xj[lane] + xi[lane + 64] * xj[lane + 64];
#pragma unroll
        for (int off = 32; off; off >>= 1) pp += __shfl_xor(pp, off);
        const float fb2 = sqv[grow] + sqv[jf] - 2.0f * pp;
        pos_eff = expf(-sqrtf(fmaxf(fb2, 1e-12f)));
      } else {
        pos_eff = pls;
      }
      if (lane == 0) {
        const float loss_i = -logf(pos_eff / (pos_eff + nls));
        const int cpa = (cp == 0) ? 1 : cp;
        atomicAdd(&blockAcc[0], loss_i);
        atomicAdd(&blockAcc[1], (cpa > cn) ? 1.0f : 0.0f);
        atomicAdd(&blockAcc[2], (float)cp);
        atomicAdd(&blockAcc[3], (float)cn);
      }
    }
  }
  __syncthreads();
  if (tid < 4) atomicAdd(&out[tid], blockAcc[tid] * (1.0f / (float)NPTS));
}

extern "C" void kernel_launch(void* const* d_in, const int* in_sizes, int n_in,
                              void* d_out, int out_size, void* d_ws, size_t ws_size,
                              hipStream_t stream) {
  const float* X = (const float*)d_in[0];
  const long long* targets = (const long long*)d_in[1];
  float* out = (float*)d_out;

  char* ws = (char*)d_ws;
  unsigned short* Xb = (unsigned short*)ws;                        // 2 MiB
  float* sqv  = (float*)(ws + (2u << 20));                         // 32 KiB
  int*   tgt  = (int*)  (ws + (2u << 20) + (32u << 10));           // 32 KiB
  int* ccount = (int*)  (ws + (2u << 20) + (64u << 10));           // 1.5 KiB
  int* j0a = ccount + NCLS;
  int* j1a = j0a + NCLS;
  float* scr = (float*)(ws + (2u << 20) + (128u << 10));           // 8192*80*4 = 2.5 MiB
  int* cscr  = (int*)  (ws + (2u << 20) + (128u << 10) + 8192u * 2 * SEG * 4);  // 64 KiB

  hipMemsetAsync(d_out, 0, 4 * sizeof(float), stream);
  prep<<<2049, 256, 0, stream>>>(X, targets, Xb, sqv, tgt, ccount, j0a, j1a);
  knn_main<<<1024, 256, 0, stream>>>(Xb, sqv, tgt, scr, cscr);
  knn_merge<<<512, 256, 0, stream>>>(scr, cscr, sqv, tgt, ccount, j0a, j1a, X, out);
}

// Round 5
// 373.370 us; speedup vs baseline: 1.2461x; 1.0396x over previous
//
#include <hip/hip_runtime.h>

#define NPTS 8192
#define DIM 128
#define NCLS 128
#define KSEL 17      // k+1 smallest define the threshold
#define ROWS 32      // rows per block (two 16-row MFMA sets)
#define CAPW 40      // per-(wave,row) LDS candidate capacity
#define SEG  32      // per-(row,quarter) scratch segment
#define NT   32      // tiles per wave (512 cols / 16)
#define BIG 3.0e38f

typedef short bf16x8 __attribute__((ext_vector_type(8)));
typedef float f32x4 __attribute__((ext_vector_type(4)));

__device__ __forceinline__ unsigned short f2bf(float f) {
  unsigned int u = __float_as_uint(f);
  u += 0x7fffu + ((u >> 16) & 1u);   // round-to-nearest-even
  return (unsigned short)(u >> 16);
}

// ---- prep: bf16 X + exact fp32 norms + distributed class stats
// packed[c]: (j0<<16)|j1 = two smallest indices of class c (init 0xFFFFFFFF)
__global__ void prep(const float* __restrict__ X, const long long* __restrict__ targets,
                     unsigned short* __restrict__ Xb, float* __restrict__ sqv,
                     int* __restrict__ tgt, int* __restrict__ ccount,
                     unsigned* __restrict__ packed) {
  const int tid = threadIdx.x;
  const int w = tid >> 6, lane = tid & 63;
  const int gw = blockIdx.x * 4 + w;
  const float* xr = X + (size_t)gw * DIM;
  float a = xr[lane], b = xr[lane + 64];
  Xb[(size_t)gw * DIM + lane] = f2bf(a);
  Xb[(size_t)gw * DIM + lane + 64] = f2bf(b);
  float s = a * a + b * b;
#pragma unroll
  for (int off = 32; off; off >>= 1) s += __shfl_xor(s, off);
  if (lane == 0) {
    sqv[gw] = s;
    int c = (int)targets[gw];
    tgt[gw] = c;
    atomicAdd(&ccount[c], 1);
    unsigned old = packed[c];
    for (;;) {                       // CAS-insert gw into the class's 2-smallest set
      unsigned j0 = old >> 16, j1 = old & 0xffffu;
      unsigned g = (unsigned)gw;
      if (g >= j1) break;
      unsigned n0 = (g < j0) ? g : j0;
      unsigned n1 = (g < j0) ? j0 : g;
      unsigned nv = (n0 << 16) | n1;
      unsigned prev = atomicCAS(&packed[c], old, nv);
      if (prev == old) break;
      old = prev;
    }
  }
}

// ---- two-sweep kNN: grid 1024 = 256 row-groups(32 rows) x 4 column-quarters.
// Wave w scans cols [quarter*2048 + w*512, +512) in 32 16-col tiles, two MFMA
// accumulator chains (row sets rbase / rbase+16) against a shared B fragment.
// val = sqj - 2*G tracked (sqi-invariant ordering within a row).
__global__ __launch_bounds__(256, 4) void knn_main(
    const unsigned short* __restrict__ Xb, const float* __restrict__ sqv,
    const int* __restrict__ tgt, float* __restrict__ scr, int* __restrict__ cscr) {
  __shared__ float sh[5120];   // union: cand[32][128] (16KB) / bufD[4][32][CAPW] (20KB)
  __shared__ int   cnt[4][ROWS];
  __shared__ float Uv[ROWS];

  const int tid = threadIdx.x;
  const int w = tid >> 6;
  const int lane = tid & 63;
  const int quad = lane >> 4;
  const int l16 = lane & 15;
  const int rg = blockIdx.x >> 2;
  const int quarter = blockIdx.x & 3;
  const int rbase = rg * ROWS;
  const int colbase = quarter * 2048 + w * 512;

  // A fragments: 2 sets x K=128. 16x16x32 bf16: A[m=lane&15][k=quad*8+j]
  bf16x8 afrag[2][4];
#pragma unroll
  for (int s = 0; s < 2; s++) {
    const unsigned short* arow = Xb + (size_t)(rbase + s * 16 + l16) * DIM + quad * 8;
#pragma unroll
    for (int kb = 0; kb < 4; kb++) afrag[s][kb] = *(const bf16x8*)(arow + kb * 32);
  }
  float sqi[2][4]; int ti[2][4];
#pragma unroll
  for (int s = 0; s < 2; s++)
#pragma unroll
    for (int r = 0; r < 4; r++) {
      int rr = rbase + s * 16 + quad * 4 + r;
      sqi[s][r] = sqv[rr]; ti[s][r] = tgt[rr];
    }

  // wave-uniform diagonal tile per set (or -1)
  int tdiag[2];
#pragma unroll
  for (int s = 0; s < 2; s++) {
    int d = rbase + s * 16 - colbase;
    tdiag[s] = (d >= 0 && d < 512) ? (d >> 4) : -1;
  }

  const unsigned short* bbase = Xb + (size_t)(colbase + l16) * DIM + quad * 8;
  const float* sqp = sqv + colbase + l16;
  const int*   tgp = tgt + colbase + l16;

  // ---- sweep 1: per-lane two smallest vals per row; register double-buffered
  float m1[2][4], m2[2][4];
#pragma unroll
  for (int s = 0; s < 2; s++)
#pragma unroll
    for (int r = 0; r < 4; r++) { m1[s][r] = BIG; m2[s][r] = BIG; }
  {
    bf16x8 bA[4], bB[4]; float sqA, sqB;
#pragma unroll
    for (int kb = 0; kb < 4; kb++) bA[kb] = *(const bf16x8*)(bbase + kb * 32);
    sqA = sqp[0];
    for (int t = 0; t < NT; t += 2) {
      {
        const unsigned short* p = bbase + (size_t)(t + 1) * (16 * DIM);
#pragma unroll
        for (int kb = 0; kb < 4; kb++) bB[kb] = *(const bf16x8*)(p + kb * 32);
        sqB = sqp[(t + 1) * 16];
      }
      {
        f32x4 a0 = {0.f,0.f,0.f,0.f}, a1 = {0.f,0.f,0.f,0.f};
#pragma unroll
        for (int kb = 0; kb < 4; kb++) {
          a0 = __builtin_amdgcn_mfma_f32_16x16x32_bf16(afrag[0][kb], bA[kb], a0, 0, 0, 0);
          a1 = __builtin_amdgcn_mfma_f32_16x16x32_bf16(afrag[1][kb], bA[kb], a1, 0, 0, 0);
        }
#pragma unroll
        for (int s = 0; s < 2; s++) {
#pragma unroll
          for (int r = 0; r < 4; r++) {
            float v = fmaf(-2.0f, (s ? a1[r] : a0[r]), sqA);
            if (t == tdiag[s] && l16 == quad * 4 + r) v = BIG;
            m2[s][r] = fminf(m2[s][r], fmaxf(m1[s][r], v));
            m1[s][r] = fminf(m1[s][r], v);
          }
        }
      }
      {
        const int tn = (t + 2 < NT) ? t + 2 : NT - 1;
        const unsigned short* p = bbase + (size_t)tn * (16 * DIM);
#pragma unroll
        for (int kb = 0; kb < 4; kb++) bA[kb] = *(const bf16x8*)(p + kb * 32);
        sqA = sqp[tn * 16];
      }
      {
        f32x4 a0 = {0.f,0.f,0.f,0.f}, a1 = {0.f,0.f,0.f,0.f};
#pragma unroll
        for (int kb = 0; kb < 4; kb++) {
          a0 = __builtin_amdgcn_mfma_f32_16x16x32_bf16(afrag[0][kb], bB[kb], a0, 0, 0, 0);
          a1 = __builtin_amdgcn_mfma_f32_16x16x32_bf16(afrag[1][kb], bB[kb], a1, 0, 0, 0);
        }
#pragma unroll
        for (int s = 0; s < 2; s++) {
#pragma unroll
          for (int r = 0; r < 4; r++) {
            float v = fmaf(-2.0f, (s ? a1[r] : a0[r]), sqB);
            if (t + 1 == tdiag[s] && l16 == quad * 4 + r) v = BIG;
            m2[s][r] = fminf(m2[s][r], fmaxf(m1[s][r], v));
            m1[s][r] = fminf(m1[s][r], v);
          }
        }
      }
    }
  }
  // publish min2: per row 4 waves x 16 lanes x 2 = 128 candidates (val-space)
#pragma unroll
  for (int s = 0; s < 2; s++)
#pragma unroll
    for (int r = 0; r < 4; r++) {
      int row = s * 16 + quad * 4 + r;
      sh[row * 128 + w * 32 + l16 * 2] = m1[s][r];
      sh[row * 128 + w * 32 + l16 * 2 + 1] = m2[s][r];
    }
  __syncthreads();

  // U[row] = 17th smallest of the 128-candidate subset (val-space; >= quarter t17)
  for (int ri = 0; ri < 8; ri++) {
    int row = w * 8 + ri;
    float a = sh[row * 128 + lane], b = sh[row * 128 + 64 + lane];
    float v17 = BIG;
    for (int round = 0; round < KSEL; round++) {
      float v = a; int idx = lane;
      if (b < v) { v = b; idx = lane | 64; }
#pragma unroll
      for (int off = 32; off; off >>= 1) {
        float ov = __shfl_xor(v, off);
        int   oi = __shfl_xor(idx, off);
        if (ov < v || (ov == v && oi < idx)) { v = ov; idx = oi; }
      }
      if ((idx & 63) == lane) { if (idx & 64) b = BIG; else a = BIG; }
      v17 = v;
    }
    if (lane == 0) Uv[row] = v17;
  }
  __syncthreads();
  float Ur[2][4];
#pragma unroll
  for (int s = 0; s < 2; s++)
#pragma unroll
    for (int r = 0; r < 4; r++) Ur[s][r] = Uv[s * 16 + quad * 4 + r];
  if (lane < ROWS) cnt[w][lane] = 0;   // wave-local; ordered before this wave's appends

  // ---- sweep 2: append val <= U (encode d2 = val + sqi, flag in sign bit)
  {
    bf16x8 bA[4], bB[4]; float sqA, sqB; int tjA, tjB;
#pragma unroll
    for (int kb = 0; kb < 4; kb++) bA[kb] = *(const bf16x8*)(bbase + kb * 32);
    sqA = sqp[0]; tjA = tgp[0];
    for (int t = 0; t < NT; t += 2) {
      {
        const unsigned short* p = bbase + (size_t)(t + 1) * (16 * DIM);
#pragma unroll
        for (int kb = 0; kb < 4; kb++) bB[kb] = *(const bf16x8*)(p + kb * 32);
        sqB = sqp[(t + 1) * 16]; tjB = tgp[(t + 1) * 16];
      }
      {
        f32x4 a0 = {0.f,0.f,0.f,0.f}, a1 = {0.f,0.f,0.f,0.f};
#pragma unroll
        for (int kb = 0; kb < 4; kb++) {
          a0 = __builtin_amdgcn_mfma_f32_16x16x32_bf16(afrag[0][kb], bA[kb], a0, 0, 0, 0);
          a1 = __builtin_amdgcn_mfma_f32_16x16x32_bf16(afrag[1][kb], bA[kb], a1, 0, 0, 0);
        }
        float vv[2][4]; bool any = false;
#pragma unroll
        for (int s = 0; s < 2; s++)
#pragma unroll
          for (int r = 0; r < 4; r++) {
            float v = fmaf(-2.0f, (s ? a1[r] : a0[r]), sqA);
            if (t == tdiag[s] && l16 == quad * 4 + r) v = BIG;
            vv[s][r] = v; any |= (v <= Ur[s][r]);
          }
        if (__any(any)) {
#pragma unroll
          for (int s = 0; s < 2; s++)
#pragma unroll
            for (int r = 0; r < 4; r++) {
              if (vv[s][r] <= Ur[s][r]) {
                int rl = s * 16 + quad * 4 + r;
                int pos = atomicAdd(&cnt[w][rl], 1);
                if (pos < CAPW) {
                  unsigned enc = __float_as_uint(fmaxf(vv[s][r] + sqi[s][r], 0.0f));
                  if (tjA == ti[s][r]) enc |= 0x80000000u;
                  sh[(w * ROWS + rl) * CAPW + pos] = __uint_as_float(enc);
                }
              }
            }
        }
      }
      {
        const int tn = (t + 2 < NT) ? t + 2 : NT - 1;
        const unsigned short* p = bbase + (size_t)tn * (16 * DIM);
#pragma unroll
        for (int kb = 0; kb < 4; kb++) bA[kb] = *(const bf16x8*)(p + kb * 32);
        sqA = sqp[tn * 16]; tjA = tgp[tn * 16];
      }
      {
        f32x4 a0 = {0.f,0.f,0.f,0.f}, a1 = {0.f,0.f,0.f,0.f};
#pragma unroll
        for (int kb = 0; kb < 4; kb++) {
          a0 = __builtin_amdgcn_mfma_f32_16x16x32_bf16(afrag[0][kb], bB[kb], a0, 0, 0, 0);
          a1 = __builtin_amdgcn_mfma_f32_16x16x32_bf16(afrag[1][kb], bB[kb], a1, 0, 0, 0);
        }
        float vv[2][4]; bool any = false;
#pragma unroll
        for (int s = 0; s < 2; s++)
#pragma unroll
          for (int r = 0; r < 4; r++) {
            float v = fmaf(-2.0f, (s ? a1[r] : a0[r]), sqB);
            if (t + 1 == tdiag[s] && l16 == quad * 4 + r) v = BIG;
            vv[s][r] = v; any |= (v <= Ur[s][r]);
          }
        if (__any(any)) {
#pragma unroll
          for (int s = 0; s < 2; s++)
#pragma unroll
            for (int r = 0; r < 4; r++) {
              if (vv[s][r] <= Ur[s][r]) {
                int rl = s * 16 + quad * 4 + r;
                int pos = atomicAdd(&cnt[w][rl], 1);
                if (pos < CAPW) {
                  unsigned enc = __float_as_uint(fmaxf(vv[s][r] + sqi[s][r], 0.0f));
                  if (tjB == ti[s][r]) enc |= 0x80000000u;
                  sh[(w * ROWS + rl) * CAPW + pos] = __uint_as_float(enc);
                }
              }
            }
        }
      }
    }
  }
  __syncthreads();

  // ---- finalize: raw-copy candidate lists (common) or 17-extract (overflow, rare)
  for (int rl = 0; rl < ROWS; rl++) {
    const int c0 = min(cnt[0][rl], CAPW), c1 = min(cnt[1][rl], CAPW),
              c2 = min(cnt[2][rl], CAPW), c3 = min(cnt[3][rl], CAPW);
    const int tot = c0 + c1 + c2 + c3;
    const int grow = rbase + rl;
    float* srow = scr + (size_t)grow * (4 * SEG) + quarter * SEG;
    if (tot <= SEG) {
      const int pre = (w > 0 ? c0 : 0) + (w > 1 ? c1 : 0) + (w > 2 ? c2 : 0);
      const int myc = (w == 0) ? c0 : ((w == 1) ? c1 : ((w == 2) ? c2 : c3));
      if (lane < myc) srow[pre + lane] = sh[(w * ROWS + rl) * CAPW + lane];
      if (tid == 0) cscr[grow * 4 + quarter] = tot;
    } else if (w == (rl & 3)) {
      float e[4]; int m[4];
#pragma unroll
      for (int ww = 0; ww < 4; ww++) {
        int n = min(cnt[ww][rl], CAPW);
        if (lane < n) {
          unsigned u = __float_as_uint(sh[(ww * ROWS + rl) * CAPW + lane]);
          m[ww] = (int)(u >> 31); e[ww] = __uint_as_float(u & 0x7fffffffu);
        } else { e[ww] = BIG; m[ww] = 0; }
      }
      for (int round = 0; round < KSEL; round++) {
        float v = e[0]; int idx = lane;
        if (e[1] < v) { v = e[1]; idx = lane | (1 << 6); }
        if (e[2] < v) { v = e[2]; idx = lane | (2 << 6); }
        if (e[3] < v) { v = e[3]; idx = lane | (3 << 6); }
#pragma unroll
        for (int off = 32; off; off >>= 1) {
          float ov = __shfl_xor(v, off);
          int   oi = __shfl_xor(idx, off);
          if (ov < v || (ov == v && oi < idx)) { v = ov; idx = oi; }
        }
        if ((idx & 63) == lane) {
          int s = idx >> 6;
          unsigned ub = __float_as_uint(e[s]);
          if (m[s]) ub |= 0x80000000u;
          srow[round] = __uint_as_float(ub);
          e[s] = BIG;
        }
      }
      if (lane == 0) cscr[grow * 4 + quarter] = KSEL;
    }
  }
}

// ---- per-row merge of 4 quarter-lists (<=128 candidates) + loss epilogue
__global__ __launch_bounds__(256) void knn_merge(
    const float* __restrict__ scr, const int* __restrict__ cscr,
    const float* __restrict__ sqv, const int* __restrict__ tgt,
    const int* __restrict__ ccount, const unsigned* __restrict__ packed,
    const float* __restrict__ X32, float* __restrict__ out) {
  __shared__ float blockAcc[4];
  const int tid = threadIdx.x;
  const int w = tid >> 6;
  const int lane = tid & 63;
  if (tid < 4) blockAcc[tid] = 0.0f;
  __syncthreads();
  for (int ri = 0; ri < 4; ri++) {
    const int grow = blockIdx.x * 16 + w * 4 + ri;
    const float* srow = scr + (size_t)grow * (4 * SEG);
    const int ca = cscr[grow * 4 + (lane >> 5)];
    const int cb = cscr[grow * 4 + 2 + (lane >> 5)];
    const int li = lane & 31;
    float e0 = BIG, e1 = BIG; int mm0 = 0, mm1 = 0;
    if (li < ca) {
      unsigned u = __float_as_uint(srow[(lane >> 5) * SEG + li]);
      mm0 = (int)(u >> 31); e0 = __uint_as_float(u & 0x7fffffffu);
    }
    if (li < cb) {
      unsigned u = __float_as_uint(srow[(2 + (lane >> 5)) * SEG + li]);
      mm1 = (int)(u >> 31); e1 = __uint_as_float(u & 0x7fffffffu);
    }
    // exact 17th smallest of the union
    float a = e0, b = e1, t17 = BIG;
    for (int round = 0; round < KSEL; round++) {
      float v = a; int idx = lane;
      if (b < v) { v = b; idx = lane | 64; }
#pragma unroll
      for (int off = 32; off; off >>= 1) {
        float ov = __shfl_xor(v, off);
        int   oi = __shfl_xor(idx, off);
        if (ov < v || (ov == v && oi < idx)) { v = ov; idx = oi; }
      }
      if ((idx & 63) == lane) { if (idx & 64) b = BIG; else a = BIG; }
      t17 = v;
    }
    bool s0 = (e0 < t17), s1 = (e1 < t17);                // strict, matches reference
    float x0 = s0 ? expf(-sqrtf(fmaxf(e0, 1e-12f))) : 0.0f;
    float x1 = s1 ? expf(-sqrtf(fmaxf(e1, 1e-12f))) : 0.0f;
    float pls = (s0 && mm0 ? x0 : 0.0f) + (s1 && mm1 ? x1 : 0.0f);
    float nls = (s0 && !mm0 ? x0 : 0.0f) + (s1 && !mm1 ? x1 : 0.0f);
    int cp = (s0 && mm0) + (s1 && mm1);
    int cn = (s0 && !mm0) + (s1 && !mm1);
#pragma unroll
    for (int off = 32; off; off >>= 1) {
      pls += __shfl_xor(pls, off); nls += __shfl_xor(nls, off);
      cp  += __shfl_xor(cp, off);  cn  += __shfl_xor(cn, off);
    }
    const int c = tgt[grow];
    const int ncl = ccount[c];
    const bool valid = (ncl > 1) && (ncl < NPTS);
    if (valid) {
      float pos_eff;
      if (cp == 0) {
        const unsigned pk = packed[c];
        const int j0 = (int)(pk >> 16), j1 = (int)(pk & 0xffffu);
        const int jf = (grow == j0) ? j1 : j0;
        const float* xi = X32 + (size_t)grow * DIM;
        const float* xj = X32 + (size_t)jf * DIM;
        float pp = xi[lane] * xj[lane] + xi[lane + 64] * xj[lane + 64];
#pragma unroll
        for (int off = 32; off; off >>= 1) pp += __shfl_xor(pp, off);
        const float fb2 = sqv[grow] + sqv[jf] - 2.0f * pp;
        pos_eff = expf(-sqrtf(fmaxf(fb2, 1e-12f)));
      } else {
        pos_eff = pls;
      }
      if (lane == 0) {
        const float loss_i = -logf(pos_eff / (pos_eff + nls));
        const int cpa = (cp == 0) ? 1 : cp;
        atomicAdd(&blockAcc[0], loss_i);
        atomicAdd(&blockAcc[1], (cpa > cn) ? 1.0f : 0.0f);
        atomicAdd(&blockAcc[2], (float)cp);
        atomicAdd(&blockAcc[3], (float)cn);
      }
    }
  }
  __syncthreads();
  if (tid < 4) atomicAdd(&out[tid], blockAcc[tid] * (1.0f / (float)NPTS));
}

extern "C" void kernel_launch(void* const* d_in, const int* in_sizes, int n_in,
                              void* d_out, int out_size, void* d_ws, size_t ws_size,
                              hipStream_t stream) {
  const float* X = (const float*)d_in[0];
  const long long* targets = (const long long*)d_in[1];
  float* out = (float*)d_out;

  char* ws = (char*)d_ws;
  unsigned short* Xb = (unsigned short*)ws;                        // 2 MiB
  float* sqv    = (float*)   (ws + (2u << 20));                    // 32 KiB
  int*   tgt    = (int*)     (ws + (2u << 20) + (32u << 10));      // 32 KiB
  int*   ccount = (int*)     (ws + (2u << 20) + (64u << 10));      // 512 B
  unsigned* packed = (unsigned*)(ws + (2u << 20) + (65u << 10));   // 512 B
  float* scr = (float*)(ws + (2u << 20) + (128u << 10));           // 8192*4*SEG*4 = 4 MiB
  int* cscr  = (int*)  (ws + (2u << 20) + (128u << 10) + (size_t)NPTS * 4 * SEG * 4); // 128 KiB

  hipMemsetAsync(d_out, 0, 4 * sizeof(float), stream);
  hipMemsetAsync(ccount, 0, NCLS * sizeof(int), stream);
  hipMemsetAsync(packed, 0xFF, NCLS * sizeof(unsigned), stream);
  prep<<<2048, 256, 0, stream>>>(X, targets, Xb, sqv, tgt, ccount, packed);
  knn_main<<<1024, 256, 0, stream>>>(Xb, sqv, tgt, scr, cscr);
  knn_merge<<<512, 256, 0, stream>>>(scr, cscr, sqv, tgt, ccount, packed, X, out);
}